// Round 8
// baseline (24773.299 us; speedup 1.0000x reference)
//
#include <hip/hip_runtime.h>
#include <stdint.h>

#define S_LEN 512
#define NB    64
#define HID   256
#define G3    768
#define SB    32768   // S_LEN * NB
#define NLAYER 6

typedef short bf16x8 __attribute__((ext_vector_type(8)));
typedef float floatx4 __attribute__((ext_vector_type(4)));
typedef unsigned long long u64;
typedef unsigned long long u64x2 __attribute__((ext_vector_type(2)));
typedef unsigned short u16;
typedef unsigned int   u32;

__device__ __forceinline__ float bf2f(u16 v) {
  u32 u = ((u32)v) << 16;
  return __builtin_bit_cast(float, u);
}
__device__ __forceinline__ u16 f2bf(float f) {
  u32 u = __builtin_bit_cast(u32, f);
  u = (u + 0x7FFFu + ((u >> 16) & 1u)) >> 16;
  return (u16)u;
}
__device__ __forceinline__ float fsigmoid(float x) {
  return __builtin_amdgcn_rcpf(1.0f + __expf(-x));
}
__device__ __forceinline__ float ftanh(float x) {
  return 1.0f - 2.0f * __builtin_amdgcn_rcpf(1.0f + __expf(x + x));
}

// ---------------------------------------------------------------------------
// detect_fp32 / cvt / write_out: dtype-adaptive input handling.
// ---------------------------------------------------------------------------
__global__ void detect_fp32(const u16* __restrict__ x, int n, int* flag) {
  __shared__ int tot;
  if (threadIdx.x == 0) tot = 0;
  __syncthreads();
  int c = 0;
  for (int i = threadIdx.x; i < n; i += blockDim.x) {
    u16 v = x[i];
    if (((v >> 7) & 0xFF) == 0xFF) ++c;
  }
  atomicAdd(&tot, c);
  __syncthreads();
  if (threadIdx.x == 0) *flag = (tot > 64) ? 1 : 0;
}

__global__ void cvt(const void* __restrict__ src, u16* __restrict__ dst,
                    int n, const int* __restrict__ flag) {
  const int stride = gridDim.x * blockDim.x;
  const bool isf32 = (*flag != 0);
  for (int i = blockIdx.x * blockDim.x + threadIdx.x; i < n; i += stride) {
    if (isf32) dst[i] = f2bf(((const float*)src)[i]);
    else       dst[i] = ((const u16*)src)[i];
  }
}

__global__ void write_out(const float* __restrict__ hNs, void* __restrict__ out,
                          int n, const int* __restrict__ flag) {
  int i = blockIdx.x * blockDim.x + threadIdx.x;
  if (i >= n) return;
  if (*flag) ((float*)out)[i] = hNs[i];
  else       ((u16*)out)[i]   = f2bf(hNs[i]);
}

// ---------------------------------------------------------------------------
// gate_gemm: preacts = A . W^T + b_ih (+ b_hh for r/z gates), written in the
// permuted gateXp layout for the 16-WG scan:
//   idx = ((((((dir*512+s)*4+bg)*2+jh)*3+g)*8+wv)*64 + lane)*4 + r
// value = preact at batch b=bg*16+quad*4+r (lane=quad*16+l15),
// col n = g*256 + jh*128 + wv*16 + l15.
// ---------------------------------------------------------------------------
__global__ __launch_bounds__(256)
void gate_gemm(const u16* __restrict__ A, const u16* __restrict__ W,
               const u16* __restrict__ bias_ih, const u16* __restrict__ bias_hh,
               u16* __restrict__ outg, int K) {
  const int m0  = blockIdx.x * 128;
  const int n0  = blockIdx.y * 128;
  const int dir = blockIdx.z;
  W       += (size_t)dir * G3 * K;
  bias_ih += (size_t)dir * G3;
  bias_hh += (size_t)dir * G3;

  __shared__ __align__(16) u16 lA[8192];
  __shared__ __align__(16) u16 lB[8192];

  const int tid  = threadIdx.x;
  const int lane = tid & 63;
  const int wv   = tid >> 6;
  const int wm   = wv & 1, wn = wv >> 1;
  const int l15  = lane & 15, quad = lane >> 4;

  floatx4 acc[4][4] = {};

  for (int k0 = 0; k0 < K; k0 += 64) {
    bf16x8 ra[4], rb[4];
#pragma unroll
    for (int i = 0; i < 4; ++i) {
      int c   = i * 256 + tid;
      int row = c >> 3;
      int kc  = (c & 7) ^ (row & 7);
      ra[i] = *(const bf16x8*)(A + (size_t)(m0 + row) * K + (k0 + kc * 8));
      rb[i] = *(const bf16x8*)(W + (size_t)(n0 + row) * K + (k0 + kc * 8));
    }
    __syncthreads();
#pragma unroll
    for (int i = 0; i < 4; ++i) {
      *(bf16x8*)(lA + (size_t)(i * 256 + tid) * 8) = ra[i];
      *(bf16x8*)(lB + (size_t)(i * 256 + tid) * 8) = rb[i];
    }
    __syncthreads();

#pragma unroll
    for (int kt = 0; kt < 2; ++kt) {
      bf16x8 af[4], bfr[4];
#pragma unroll
      for (int mt = 0; mt < 4; ++mt) {
        int row = wm * 64 + mt * 16 + l15;
        int ch  = row * 8 + ((kt * 4 + quad) ^ (row & 7));
        af[mt] = *(const bf16x8*)(lA + ch * 8);
      }
#pragma unroll
      for (int nt = 0; nt < 4; ++nt) {
        int row = wn * 64 + nt * 16 + l15;
        int ch  = row * 8 + ((kt * 4 + quad) ^ (row & 7));
        bfr[nt] = *(const bf16x8*)(lB + ch * 8);
      }
#pragma unroll
      for (int mt = 0; mt < 4; ++mt)
#pragma unroll
        for (int nt = 0; nt < 4; ++nt)
          acc[mt][nt] = __builtin_amdgcn_mfma_f32_16x16x32_bf16(
              af[mt], bfr[nt], acc[mt][nt], 0, 0, 0);
    }
  }
  __syncthreads();

  const int sblk = (m0 >> 6) + wm;   // s index; bg = mt
#pragma unroll
  for (int nt = 0; nt < 4; ++nt) {
    int n   = n0 + wn * 64 + nt * 16 + l15;
    int g   = n >> 8;
    int j   = n & 255;
    int jh  = j >> 7;
    int wvs = (j >> 4) & 7;
    float bv = bf2f(bias_ih[n]) + ((n < 512) ? bf2f(bias_hh[n]) : 0.0f);
#pragma unroll
    for (int mt = 0; mt < 4; ++mt) {
#pragma unroll
      for (int r = 0; r < 4; ++r) {
        size_t P = ((((((((size_t)dir * 512 + sblk) * 4 + mt) * 2 + jh) * 3 + g)
                          * 8 + wvs) * 64 + quad * 16 + l15)) * 4 + r;
        outg[P] = f2bf(acc[mt][nt][r] + bv);
      }
    }
  }
}

// ---------------------------------------------------------------------------
// gru_scan v5.1: 16 WGs. blk = jh*8 + (dir + 2*bg); partner = blk ^ 8.
// Each WG owns 3 gates x 128 j-cols (192 KB weights = 24 pinned bf16x8/thread,
// feasible residency). Cross-WG h exchange via device-scope atomics in ws:
//   publish own 4 KB half + monotonic flag; consume partner half directly
//   into A-fragments. MFMA split: own-k half first (overlaps partner's
//   latency), partner-k half after the spin.
// v5.1 fix: flags/gbuf moved OUT of the hNs fp32 region (round-7 overlap
// clobbered flags and minted bf16-NaN from fp32 mantissa halves in gbuf).
// ---------------------------------------------------------------------------
__global__ __launch_bounds__(512)
void gru_scan(const u16* __restrict__ gateXp,  // permuted, 2*SB*G3
              const u16* __restrict__ Whh,     // [2][768][256] (this layer)
              const u16* __restrict__ Bhh,     // [2][768]
              const u16* __restrict__ H0,      // [12][64][256] bf16
              u16* __restrict__ layerOut,      // [SB][512] bf16 row-major
              float* __restrict__ hNs,         // fp32 staging [12][64][256]
              u16* __restrict__ gbuf,          // [16 slots][2][16*128]
              u32* __restrict__ flags,         // [16 slots][32]
              int layer) {
  const int blk  = blockIdx.x;
  const int pair = blk & 7;
  const int jh   = blk >> 3;
  const int dir  = pair & 1;
  const int bg   = pair >> 1;
  const int tid  = threadIdx.x;
  const int lane = tid & 63;
  const int wv   = tid >> 6;
  const int l15  = lane & 15, quad = lane >> 4;
  const int jloc = wv * 16 + l15;

  __shared__ __align__(16) u16 hbuf[2][16 * 128];  // own half, swizzled 16B chunks

  const int slot  = pair * 2 + jh;
  const int pslot = pair * 2 + (1 - jh);
  u16* gOwn = gbuf + (size_t)slot * 2 * 2048;
  u16* gPar = gbuf + (size_t)pslot * 2 * 2048;
  u32* flagMine = flags + slot * 32;
  u32* flagPar  = flags + pslot * 32;
  const u32 seq = (u32)layer * 600;

  const u16* Wd = Whh + (size_t)dir * G3 * HID;

  // ---- stationary weights: 24 fragments (3 gates x 8 kt), 96 regs ----
  bf16x8 wfr[8][3];
#pragma unroll
  for (int g = 0; g < 3; ++g) {
    int nrow = g * 256 + jh * 128 + jloc;
#pragma unroll
    for (int kt = 0; kt < 8; ++kt)
      wfr[kt][g] = *(const bf16x8*)(Wd + (size_t)nrow * HID + kt * 32 + quad * 8);
  }
#pragma unroll
  for (int kt = 0; kt < 8; ++kt)
#pragma unroll
    for (int g = 0; g < 3; ++g)
      asm volatile("" : "+v"(wfr[kt][g]));

  const float bh = bf2f(Bhh[dir * G3 + 512 + jh * 128 + jloc]);

  // ---- h0: hprev regs + hbuf[1] + publish gbuf parity 1 ----
  float hprev[4];
#pragma unroll
  for (int r = 0; r < 4; ++r) {
    int m = quad * 4 + r;
    u16 hv = H0[((size_t)(layer * 2 + dir) * NB + bg * 16 + m) * HID +
                jh * 128 + jloc];
    hprev[r] = bf2f(hv);
    int ch = jloc >> 3;
    int sw = (ch & 8) | ((ch & 7) ^ (m & 7));
    *(u16*)((char*)hbuf[1] + m * 256 + sw * 16 + (jloc & 7) * 2) = hv;
    __hip_atomic_store(&gOwn[2048 + m * 128 + jloc], hv, __ATOMIC_RELAXED,
                       __HIP_MEMORY_SCOPE_AGENT);
  }
  __syncthreads();
  if (tid == 0)
    __hip_atomic_store(flagMine, seq + 1, __ATOMIC_RELAXED,
                       __HIP_MEMORY_SCOPE_AGENT);

  // layerOut staging identity: thread -> (row ms, 8B half-chunk cs) of own half
  const int ms  = tid >> 5;
  const int cs  = tid & 31;
  const int c16 = cs >> 1;
  const int swc = (c16 & 8) | ((c16 & 7) ^ (ms & 7));
  u16* loutBase =
      layerOut + (size_t)(bg * 16 + ms) * 512 + dir * 256 + jh * 128 + cs * 4;

  for (int t = 0; t < S_LEN; ++t) {
    const int s   = dir ? (S_LEN - 1 - t) : t;
    const int cur = (t & 1) ^ 1;

    // ---- staged layerOut store for h(t-1) ----
    if (t > 0) {
      const int sp = dir ? (S_LEN - t) : (t - 1);
      u64 hv = *(const u64*)((const char*)hbuf[cur] + ms * 256 + swc * 16 +
                             (cs & 1) * 8);
      *(u64*)(loutBase + (size_t)sp * NB * 512) = hv;
    }

    // ---- x-gate loads (overlap MFMA + exchange) ----
    const u16* xp =
        gateXp +
        ((((((size_t)dir * 512 + s) * 4 + bg) * 2 + jh) * 24 + wv) * 64 + lane) * 4;
    u64 x0 = *(const u64*)(xp);
    u64 x1 = *(const u64*)(xp + 2048);
    u64 x2 = *(const u64*)(xp + 4096);

    floatx4 acc[3];
    {
      floatx4 z = {0.0f, 0.0f, 0.0f, 0.0f};
      floatx4 b = {bh, bh, bh, bh};
      acc[0] = z; acc[1] = z; acc[2] = b;
    }

    // ---- MFMA part 1: own k-half from LDS ----
#pragma unroll
    for (int ktl = 0; ktl < 4; ++ktl) {
      int c  = ktl * 4 + quad;
      int sw = (c & 8) | ((c & 7) ^ (l15 & 7));
      bf16x8 af = *(const bf16x8*)((const char*)hbuf[cur] + l15 * 256 + sw * 16);
#pragma unroll
      for (int g = 0; g < 3; ++g)
        acc[g] = __builtin_amdgcn_mfma_f32_16x16x32_bf16(af, wfr[jh * 4 + ktl][g],
                                                         acc[g], 0, 0, 0);
    }

    // ---- spin for partner h(t-1), then part 2 direct from gbuf ----
    {
      const u32 tgt = seq + (u32)t + 1;
      while (__hip_atomic_load(flagPar, __ATOMIC_RELAXED,
                               __HIP_MEMORY_SCOPE_AGENT) < tgt)
        __builtin_amdgcn_s_sleep(2);
    }
    asm volatile("" ::: "memory");   // no compiler hoist of data loads above spin
    const u16* gp = gPar + ((t + 1) & 1) * 2048;
#pragma unroll
    for (int ktl = 0; ktl < 4; ++ktl) {
      u64* a = (u64*)(gp + l15 * 128 + ktl * 32 + quad * 8);
      u64 lo = __hip_atomic_load(a, __ATOMIC_RELAXED, __HIP_MEMORY_SCOPE_AGENT);
      u64 hi = __hip_atomic_load(a + 1, __ATOMIC_RELAXED, __HIP_MEMORY_SCOPE_AGENT);
      u64x2 p = {lo, hi};
      bf16x8 af = __builtin_bit_cast(bf16x8, p);
#pragma unroll
      for (int g = 0; g < 3; ++g)
        acc[g] = __builtin_amdgcn_mfma_f32_16x16x32_bf16(
            af, wfr[(1 - jh) * 4 + ktl][g], acc[g], 0, 0, 0);
    }

    // ---- gate phase (4 h-elements/thread) + publish ----
    char* hwr  = (char*)hbuf[t & 1];
    u16*  gpub = gOwn + (t & 1) * 2048;
#pragma unroll
    for (int r = 0; r < 4; ++r) {
      int m = quad * 4 + r;
      float xr = bf2f((u16)(x0 >> (16 * r)));
      float xz = bf2f((u16)(x1 >> (16 * r)));
      float xn = bf2f((u16)(x2 >> (16 * r)));
      float rg = fsigmoid(xr + acc[0][r]);
      float zg = fsigmoid(xz + acc[1][r]);
      float ng = ftanh(xn + rg * acc[2][r]);
      float h  = (1.0f - zg) * ng + zg * hprev[r];
      hprev[r] = h;
      u16 hb = f2bf(h);
      int ch = jloc >> 3;
      int sw = (ch & 8) | ((ch & 7) ^ (m & 7));
      *(u16*)(hwr + m * 256 + sw * 16 + (jloc & 7) * 2) = hb;
      __hip_atomic_store(&gpub[m * 128 + jloc], hb, __ATOMIC_RELAXED,
                         __HIP_MEMORY_SCOPE_AGENT);
    }

    __syncthreads();   // drains each wave's LDS + vmem (incl. publishes)
    if (tid == 0)
      __hip_atomic_store(flagMine, seq + (u32)t + 2, __ATOMIC_RELAXED,
                         __HIP_MEMORY_SCOPE_AGENT);
  }

  // ---- epilogue: h(S-1) -> layerOut + hNs ----
  {
    const int sp = dir ? 0 : (S_LEN - 1);
    u64 hv = *(const u64*)((const char*)hbuf[1] + ms * 256 + swc * 16 +
                           (cs & 1) * 8);
    *(u64*)(loutBase + (size_t)sp * NB * 512) = hv;
#pragma unroll
    for (int r = 0; r < 4; ++r) {
      int m = quad * 4 + r;
      hNs[((size_t)(layer * 2 + dir) * NB + bg * 16 + m) * HID + jh * 128 + jloc] =
          hprev[r];
    }
  }
}

// ---------------------------------------------------------------------------
extern "C" void kernel_launch(void* const* d_in, const int* in_sizes, int n_in,
                              void* d_out, int out_size, void* d_ws, size_t ws_size,
                              hipStream_t stream) {
  (void)n_in; (void)ws_size;
  char* ws = (char*)d_ws;
  // ws layout:
  //   [0, 4K)            flag
  //   [4K, ~772K)        hNs fp32 staging (786432 B)
  //   [832K, 834K)       flags (16 slots x 128 B)      -- OUTSIDE hNs now
  //   [840K, 968K)       gbuf  (16 slots x 8 KB)       -- OUTSIDE hNs now
  //   [1M, ~14M)         bf16 copies: h0,wih0,wih,whh,bih,bhh
  //   [16M, 112M)        gateXp
  //   [112M, 144M)       bufA ; [144M,176M) bufB (xC aliases bufB)
  int*   flag  = (int*)ws;
  float* hNs   = (float*)(ws + 4096);
  u32*   flags = (u32*)(ws + 851968);          // 832 KB
  u16*   gbuf  = (u16*)(ws + 860160);          // 840 KB
  u16*   h0C   = (u16*)(ws + (1u << 20));
  u16*   wih0C = h0C   + 196608;
  u16*   wihC  = wih0C + 196608;
  u16*   whhC  = wihC  + 3932160;
  u16*   bihC  = whhC  + 2359296;
  u16*   bhhC  = bihC  + 9216;
  u16*   gateXp = (u16*)(ws + (16u  << 20));
  u16*   bufA   = (u16*)(ws + (112u << 20));
  u16*   bufB   = (u16*)(ws + (144u << 20));
  u16*   xC     = bufB;  // aliased; layer-0 gemm consumes it before bufB written

  hipMemsetAsync(flags, 0, 16 * 128, stream);

  detect_fp32<<<1, 1024, 0, stream>>>((const u16*)d_in[0], 262144, flag);
  cvt<<<512, 256, 0, stream>>>(d_in[0], xC,    in_sizes[0], flag);
  cvt<<<256, 256, 0, stream>>>(d_in[1], h0C,   in_sizes[1], flag);
  cvt<<<256, 256, 0, stream>>>(d_in[2], wih0C, in_sizes[2], flag);
  cvt<<<512, 256, 0, stream>>>(d_in[3], wihC,  in_sizes[3], flag);
  cvt<<<512, 256, 0, stream>>>(d_in[4], whhC,  in_sizes[4], flag);
  cvt<<< 64, 256, 0, stream>>>(d_in[5], bihC,  in_sizes[5], flag);
  cvt<<< 64, 256, 0, stream>>>(d_in[6], bhhC,  in_sizes[6], flag);

  for (int layer = 0; layer < NLAYER; ++layer) {
    const u16* inp = (layer == 0) ? xC : ((layer & 1) ? bufA : bufB);
    u16* outBuf    = (layer & 1) ? bufB : bufA;

    const int K = (layer == 0) ? 128 : 512;
    const u16* W = (layer == 0) ? wih0C
                                : (wihC + (size_t)(layer - 1) * 2 * G3 * 512);
    dim3 grid(256, 6, 2);
    gate_gemm<<<grid, 256, 0, stream>>>(inp, W, bihC + (size_t)layer * 2 * G3,
                                        bhhC + (size_t)layer * 2 * G3, gateXp, K);
    gru_scan<<<16, 512, 0, stream>>>(gateXp, whhC + (size_t)layer * 2 * G3 * HID,
                                     bhhC + (size_t)layer * 2 * G3, h0C,
                                     outBuf, hNs, gbuf, flags, layer);
  }
  write_out<<<(out_size + 255) / 256, 256, 0, stream>>>(hNs, d_out, out_size, flag);
}